// Round 1
// baseline (3557.040 us; speedup 1.0000x reference)
//
#include <hip/hip_runtime.h>
#include <math.h>

#define N_NODES 50000
#define N_EDGES 800000
#define ENC 64
#define ROUNDS 3
#define NEG_SLOPE 0.2f

typedef unsigned int u32;

// monotonic float<->uint mapping for atomicMax on signed floats; 0 == "-inf" sentinel
__device__ __forceinline__ u32 ford(float f) {
  u32 u = __float_as_uint(f);
  return (u & 0x80000000u) ? ~u : (u | 0x80000000u);
}
__device__ __forceinline__ float funord(u32 u) {
  u32 b = (u & 0x80000000u) ? (u ^ 0x80000000u) : ~u;
  return __uint_as_float(b);
}

__device__ __forceinline__ float lrelu(float m) {
  return m > 0.f ? m : NEG_SLOPE * m;
}

// ---------------- CSR build ----------------
__global__ void k_hist(const int* __restrict__ dst, int* __restrict__ deg) {
  int i = blockIdx.x * blockDim.x + threadIdx.x;
  int stride = gridDim.x * blockDim.x;
  for (; i < N_EDGES; i += stride) atomicAdd(&deg[dst[i]], 1);
}

// cursor[] holds degrees on entry; on exit row_start[0..N] = exclusive scan,
// cursor[i] = row_start[i] (scatter cursors). Single block of 1024.
__global__ void __launch_bounds__(1024) k_scan(int* __restrict__ cursor,
                                               int* __restrict__ row_start) {
  __shared__ int part[1024];
  const int T = 1024;
  const int CH = (N_NODES + T - 1) / T;  // 49
  int t = threadIdx.x;
  int start = t * CH;
  int end = min(start + CH, N_NODES);
  int sum = 0;
  for (int i = start; i < end; ++i) sum += cursor[i];
  part[t] = sum;
  __syncthreads();
  for (int off = 1; off < T; off <<= 1) {
    int v = (t >= off) ? part[t - off] : 0;
    __syncthreads();
    part[t] += v;
    __syncthreads();
  }
  int run = part[t] - sum;  // exclusive base
  for (int i = start; i < end; ++i) {
    int d = cursor[i];
    row_start[i] = run;
    cursor[i] = run;
    run += d;
  }
  if (t == T - 1) row_start[N_NODES] = part[T - 1];
}

__global__ void k_scatter(const int* __restrict__ src, const int* __restrict__ dst,
                          int* __restrict__ cursor, int* __restrict__ eid,
                          int* __restrict__ srcs) {
  int i = blockIdx.x * blockDim.x + threadIdx.x;
  int stride = gridDim.x * blockDim.x;
  for (; i < N_EDGES; i += stride) {
    int d = dst[i];
    int pos = atomicAdd(&cursor[d], 1);
    eid[pos] = i;
    srcs[pos] = src[i];
  }
}

// ---------------- tiny weight fold: W_comb = W_edge @ We, b_comb = b_edge @ We ----
__global__ void k_wcomb(const float* __restrict__ W_edge, const float* __restrict__ b_edge,
                        const float* __restrict__ aWe, const float* __restrict__ cWe,
                        float* __restrict__ wcomb, float* __restrict__ bcomb) {
  int t = threadIdx.x;  // 256
  int i = t >> 6, d = t & 63;
  for (int sr = 0; sr < 6; ++sr) {
    const float* We = (sr < 3) ? (aWe + sr * ENC * ENC) : (cWe + (sr - 3) * ENC * ENC);
    float sum = 0.f;
    for (int k = 0; k < ENC; ++k) sum += W_edge[i * ENC + k] * We[k * ENC + d];
    wcomb[sr * 4 * ENC + i * ENC + d] = sum;
    if (t < ENC) {
      float bs = 0.f;
      for (int k = 0; k < ENC; ++k) bs += b_edge[k] * We[k * ENC + t];
      bcomb[sr * ENC + t] = bs;
    }
  }
}

// ---------------- node encoder: h0 = x @ W_node + b_node (K=8) ----------------
__global__ void k_encode(const float* __restrict__ x, const float* __restrict__ Wn,
                         const float* __restrict__ bn, float* __restrict__ h0) {
  __shared__ float lw[8 * ENC];
  __shared__ float lb[ENC];
  int t = threadIdx.x;
  for (int i = t; i < 8 * ENC; i += blockDim.x) lw[i] = Wn[i];
  if (t < ENC) lb[t] = bn[t];
  __syncthreads();
  int wid = t >> 6, lane = t & 63;
  int nwaves = (blockDim.x >> 6) * gridDim.x;
  int w = blockIdx.x * (blockDim.x >> 6) + wid;
  for (int n = w; n < N_NODES; n += nwaves) {
    const float4* xr4 = (const float4*)(x + n * 8);
    float4 a = xr4[0], b = xr4[1];
    float acc = lb[lane];
    acc += a.x * lw[0 * ENC + lane] + a.y * lw[1 * ENC + lane] +
           a.z * lw[2 * ENC + lane] + a.w * lw[3 * ENC + lane];
    acc += b.x * lw[4 * ENC + lane] + b.y * lw[5 * ENC + lane] +
           b.z * lw[6 * ENC + lane] + b.w * lw[7 * ENC + lane];
    h0[n * ENC + lane] = acc;
  }
}

// ---------------- per-round double GEMM: xl = h@Wl, xr = h@Wr ----------------
__global__ void k_gemm2(const float* __restrict__ hin, const float* __restrict__ Wl,
                        const float* __restrict__ Wr, float* __restrict__ xl,
                        float* __restrict__ xr) {
  __shared__ float lwl[ENC * ENC];
  __shared__ float lwr[ENC * ENC];
  int t = threadIdx.x;
  for (int i = t; i < ENC * ENC; i += blockDim.x) {
    lwl[i] = Wl[i];
    lwr[i] = Wr[i];
  }
  __syncthreads();
  int wid = t >> 6, lane = t & 63;
  int nwaves = (blockDim.x >> 6) * gridDim.x;
  int w = blockIdx.x * (blockDim.x >> 6) + wid;
  for (int n = w; n < N_NODES; n += nwaves) {
    const float4* hr = (const float4*)(hin + n * ENC);
    float aL = 0.f, aR = 0.f;
#pragma unroll
    for (int k4 = 0; k4 < 16; ++k4) {
      float4 hv = hr[k4];
      int k = k4 * 4;
      aL += hv.x * lwl[(k + 0) * ENC + lane]; aR += hv.x * lwr[(k + 0) * ENC + lane];
      aL += hv.y * lwl[(k + 1) * ENC + lane]; aR += hv.y * lwr[(k + 1) * ENC + lane];
      aL += hv.z * lwl[(k + 2) * ENC + lane]; aR += hv.z * lwr[(k + 2) * ENC + lane];
      aL += hv.w * lwl[(k + 3) * ENC + lane]; aR += hv.w * lwr[(k + 3) * ENC + lane];
    }
    xl[n * ENC + lane] = aL;
    xr[n * ENC + lane] = aR;
  }
}

// ---------------- edge scores: s[e] = att . lrelu(xl[src]+xr[dst]+ea@Wc+bc) ----
__global__ void k_score(const float* __restrict__ xl, const float* __restrict__ xr,
                        const float* __restrict__ ea, const int* __restrict__ src,
                        const int* __restrict__ dst, const float* __restrict__ wc,
                        const float* __restrict__ bc, const float* __restrict__ att,
                        float* __restrict__ s, u32* __restrict__ smax) {
  __shared__ float lwc[4 * ENC];
  __shared__ float lbc[ENC];
  __shared__ float latt[ENC];
  int t = threadIdx.x;
  for (int i = t; i < 4 * ENC; i += blockDim.x) lwc[i] = wc[i];
  if (t < ENC) {
    lbc[t] = bc[t];
    latt[t] = att[t];
  }
  __syncthreads();
  int g = t >> 4, sub = t & 15;
  int gpb = blockDim.x >> 4;
  int e0 = blockIdx.x * gpb + g, stride = gridDim.x * gpb;
  int c = sub * 4;
  for (int e = e0; e < N_EDGES; e += stride) {
    int sn = src[e], dn = dst[e];
    float4 av = ((const float4*)ea)[e];
    float4 lv = ((const float4*)xl)[sn * 16 + sub];
    float4 rv = ((const float4*)xr)[dn * 16 + sub];
    float m0 = lv.x + rv.x + lbc[c + 0] + av.x * lwc[0 * ENC + c + 0] + av.y * lwc[1 * ENC + c + 0] + av.z * lwc[2 * ENC + c + 0] + av.w * lwc[3 * ENC + c + 0];
    float m1 = lv.y + rv.y + lbc[c + 1] + av.x * lwc[0 * ENC + c + 1] + av.y * lwc[1 * ENC + c + 1] + av.z * lwc[2 * ENC + c + 1] + av.w * lwc[3 * ENC + c + 1];
    float m2 = lv.z + rv.z + lbc[c + 2] + av.x * lwc[0 * ENC + c + 2] + av.y * lwc[1 * ENC + c + 2] + av.z * lwc[2 * ENC + c + 2] + av.w * lwc[3 * ENC + c + 2];
    float m3 = lv.w + rv.w + lbc[c + 3] + av.x * lwc[0 * ENC + c + 3] + av.y * lwc[1 * ENC + c + 3] + av.z * lwc[2 * ENC + c + 3] + av.w * lwc[3 * ENC + c + 3];
    float p = lrelu(m0) * latt[c + 0] + lrelu(m1) * latt[c + 1] +
              lrelu(m2) * latt[c + 2] + lrelu(m3) * latt[c + 3];
    p += __shfl_xor(p, 1);
    p += __shfl_xor(p, 2);
    p += __shfl_xor(p, 4);
    p += __shfl_xor(p, 8);
    if (sub == 0) {
      s[e] = p;
      atomicMax(&smax[dn], ford(p));
    }
  }
}

// ---------------- per-dst softmax + weighted aggregate (one wave per node) ----
template <int RELU>
__global__ void k_aggr(const int* __restrict__ row_start, const int* __restrict__ eid,
                       const int* __restrict__ srcs, const float* __restrict__ s,
                       const u32* __restrict__ smax, const float* __restrict__ xl,
                       const float* __restrict__ b, float* __restrict__ hout) {
  int t = threadIdx.x;
  int wid = t >> 6, lane = t & 63;
  int nw = (blockDim.x >> 6) * gridDim.x;
  int w = blockIdx.x * (blockDim.x >> 6) + wid;
  for (int n = w; n < N_NODES; n += nw) {
    int rs = row_start[n], re = row_start[n + 1];
    float bv = b[lane];
    float outv;
    if (re > rs) {
      float mx = funord(smax[n]);
      float acc = 0.f, den = 0.f;
      for (int i = rs; i < re; ++i) {
        int e = eid[i];
        int sn = srcs[i];
        float ex = __expf(s[e] - mx);
        den += ex;
        acc += ex * xl[sn * ENC + lane];
      }
      outv = acc / den + bv;
    } else {
      outv = bv;  // empty neighborhood: segment sums are 0, out = b
    }
    if (RELU) outv = fmaxf(outv, 0.f);
    hout[n * ENC + lane] = outv;
  }
}

// ---------------- decoders ----------------
__global__ void k_act(const float* __restrict__ ha, const float* __restrict__ Wa,
                      const float* __restrict__ ba, float* __restrict__ out) {
  int t = threadIdx.x;
  int wid = t >> 6, lane = t & 63;
  int nw = (blockDim.x >> 6) * gridDim.x;
  int w = blockIdx.x * (blockDim.x >> 6) + wid;
  for (int n = w; n < N_NODES; n += nw) {
    float hv = ha[n * ENC + lane];
#pragma unroll
    for (int j = 0; j < 5; ++j) {
      float p = hv * Wa[lane * 5 + j];
      p += __shfl_xor(p, 1);
      p += __shfl_xor(p, 2);
      p += __shfl_xor(p, 4);
      p += __shfl_xor(p, 8);
      p += __shfl_xor(p, 16);
      p += __shfl_xor(p, 32);
      if (lane == 0) out[n * 6 + j] = tanhf(p + ba[j]);
    }
  }
}

__global__ void k_val(const float* __restrict__ hc, const float* __restrict__ Wv,
                      const float* __restrict__ bv, float* __restrict__ out) {
  int t = threadIdx.x;
  int wid = t >> 6, lane = t & 63;
  int nw = (blockDim.x >> 6) * gridDim.x;
  int w = blockIdx.x * (blockDim.x >> 6) + wid;
  for (int n = w; n < N_NODES; n += nw) {
    float p = hc[n * ENC + lane] * Wv[lane];
    p += __shfl_xor(p, 1);
    p += __shfl_xor(p, 2);
    p += __shfl_xor(p, 4);
    p += __shfl_xor(p, 8);
    p += __shfl_xor(p, 16);
    p += __shfl_xor(p, 32);
    if (lane == 0) out[n * 6 + 5] = p + bv[0];
  }
}

extern "C" void kernel_launch(void* const* d_in, const int* in_sizes, int n_in,
                              void* d_out, int out_size, void* d_ws, size_t ws_size,
                              hipStream_t stream) {
  const float* x    = (const float*)d_in[0];
  const float* ea   = (const float*)d_in[1];
  const float* Wn   = (const float*)d_in[2];
  const float* bn   = (const float*)d_in[3];
  const float* Wedg = (const float*)d_in[4];
  const float* bedg = (const float*)d_in[5];
  const float* aWl  = (const float*)d_in[6];
  const float* aWr  = (const float*)d_in[7];
  const float* aWe  = (const float*)d_in[8];
  const float* aAtt = (const float*)d_in[9];
  const float* aB   = (const float*)d_in[10];
  const float* cWl  = (const float*)d_in[11];
  const float* cWr  = (const float*)d_in[12];
  const float* cWe  = (const float*)d_in[13];
  const float* cAtt = (const float*)d_in[14];
  const float* cB   = (const float*)d_in[15];
  const float* Wa   = (const float*)d_in[16];
  const float* ba   = (const float*)d_in[17];
  const float* Wv   = (const float*)d_in[18];
  const float* bv   = (const float*)d_in[19];
  const int* src    = (const int*)d_in[20];
  const int* dst    = (const int*)d_in[21];
  float* out = (float*)d_out;

  char* w = (char*)d_ws;
  size_t off = 0;
  auto alloc = [&](size_t bytes) -> char* {
    char* p = w + off;
    off = (off + bytes + 255) & ~(size_t)255;
    return p;
  };
  float* h0 = (float*)alloc((size_t)N_NODES * ENC * 4);
  float* h  = (float*)alloc((size_t)N_NODES * ENC * 4);
  float* xl = (float*)alloc((size_t)N_NODES * ENC * 4);
  float* xr = (float*)alloc((size_t)N_NODES * ENC * 4);
  float* s  = (float*)alloc((size_t)N_EDGES * 4);
  int* eid  = (int*)alloc((size_t)N_EDGES * 4);
  int* srcs = (int*)alloc((size_t)N_EDGES * 4);
  int* row_start = (int*)alloc((size_t)(N_NODES + 1) * 4);
  int* cursor    = (int*)alloc((size_t)N_NODES * 4);
  u32* smax      = (u32*)alloc((size_t)N_NODES * 4);
  float* wcomb   = (float*)alloc(6 * 4 * ENC * 4);
  float* bcomb   = (float*)alloc(6 * ENC * 4);

  // ---- CSR build (per-launch, deterministic up to fp-neutral edge order) ----
  hipMemsetAsync(cursor, 0, (size_t)N_NODES * 4, stream);
  k_hist<<<2048, 256, 0, stream>>>(dst, cursor);
  k_scan<<<1, 1024, 0, stream>>>(cursor, row_start);
  k_scatter<<<2048, 256, 0, stream>>>(src, dst, cursor, eid, srcs);

  // ---- folded edge weights + encoder ----
  k_wcomb<<<1, 256, 0, stream>>>(Wedg, bedg, aWe, cWe, wcomb, bcomb);
  k_encode<<<512, 256, 0, stream>>>(x, Wn, bn, h0);

  for (int st = 0; st < 2; ++st) {
    const float* Wl = st ? cWl : aWl;
    const float* Wr = st ? cWr : aWr;
    const float* At = st ? cAtt : aAtt;
    const float* B  = st ? cB : aB;
    for (int r = 0; r < ROUNDS; ++r) {
      const float* hin = (r == 0) ? h0 : h;
      k_gemm2<<<1024, 256, 0, stream>>>(hin, Wl + r * ENC * ENC, Wr + r * ENC * ENC, xl, xr);
      hipMemsetAsync(smax, 0, (size_t)N_NODES * 4, stream);
      k_score<<<4096, 256, 0, stream>>>(xl, xr, ea, src, dst,
                                        wcomb + (st * 3 + r) * 4 * ENC,
                                        bcomb + (st * 3 + r) * ENC,
                                        At + r * ENC, s, smax);
      if (r < ROUNDS - 1)
        k_aggr<1><<<2048, 256, 0, stream>>>(row_start, eid, srcs, s, smax, xl, B + r * ENC, h);
      else
        k_aggr<0><<<2048, 256, 0, stream>>>(row_start, eid, srcs, s, smax, xl, B + r * ENC, h);
    }
    if (st == 0)
      k_act<<<1024, 256, 0, stream>>>(h, Wa, ba, out);
    else
      k_val<<<1024, 256, 0, stream>>>(h, Wv, bv, out);
  }
}

// Round 2
// 1525.800 us; speedup vs baseline: 2.3313x; 2.3313x over previous
//
#include <hip/hip_runtime.h>
#include <math.h>

#define N_NODES 50000
#define N_EDGES 800000
#define ENC 64
#define ROUNDS 3
#define NEG_SLOPE 0.2f

typedef unsigned int u32;

// monotonic float<->uint mapping for atomicMax on signed floats; 0 == "-inf" sentinel
__device__ __forceinline__ u32 ford(float f) {
  u32 u = __float_as_uint(f);
  return (u & 0x80000000u) ? ~u : (u | 0x80000000u);
}
__device__ __forceinline__ float funord(u32 u) {
  u32 b = (u & 0x80000000u) ? (u ^ 0x80000000u) : ~u;
  return __uint_as_float(b);
}

__device__ __forceinline__ float lrelu(float m) {
  return m > 0.f ? m : NEG_SLOPE * m;
}

// ---------------- CSR build ----------------
__global__ void k_hist(const int* __restrict__ dst, int* __restrict__ deg) {
  int i = blockIdx.x * blockDim.x + threadIdx.x;
  int stride = gridDim.x * blockDim.x;
  for (; i < N_EDGES; i += stride) atomicAdd(&deg[dst[i]], 1);
}

// cursor[] holds degrees on entry; on exit row_start[0..N] = exclusive scan,
// cursor[i] = row_start[i] (scatter cursors). Single block of 1024.
__global__ void __launch_bounds__(1024) k_scan(int* __restrict__ cursor,
                                               int* __restrict__ row_start) {
  __shared__ int part[1024];
  const int T = 1024;
  const int CH = (N_NODES + T - 1) / T;  // 49
  int t = threadIdx.x;
  int start = t * CH;
  int end = min(start + CH, N_NODES);
  int sum = 0;
  for (int i = start; i < end; ++i) sum += cursor[i];
  part[t] = sum;
  __syncthreads();
  for (int off = 1; off < T; off <<= 1) {
    int v = (t >= off) ? part[t - off] : 0;
    __syncthreads();
    part[t] += v;
    __syncthreads();
  }
  int run = part[t] - sum;  // exclusive base
  for (int i = start; i < end; ++i) {
    int d = cursor[i];
    row_start[i] = run;
    cursor[i] = run;
    run += d;
  }
  if (t == T - 1) row_start[N_NODES] = part[T - 1];
}

__global__ void k_scatter(const int* __restrict__ src, const int* __restrict__ dst,
                          int* __restrict__ cursor, int* __restrict__ eid,
                          int* __restrict__ srcs) {
  int i = blockIdx.x * blockDim.x + threadIdx.x;
  int stride = gridDim.x * blockDim.x;
  for (; i < N_EDGES; i += stride) {
    int d = dst[i];
    int pos = atomicAdd(&cursor[d], 1);
    eid[pos] = i;
    srcs[pos] = src[i];
  }
}

// ---------------- tiny weight fold: W_comb = W_edge @ We, b_comb = b_edge @ We ----
__global__ void k_wcomb(const float* __restrict__ W_edge, const float* __restrict__ b_edge,
                        const float* __restrict__ aWe, const float* __restrict__ cWe,
                        float* __restrict__ wcomb, float* __restrict__ bcomb) {
  int t = threadIdx.x;  // 256
  int i = t >> 6, d = t & 63;
  for (int sr = 0; sr < 6; ++sr) {
    const float* We = (sr < 3) ? (aWe + sr * ENC * ENC) : (cWe + (sr - 3) * ENC * ENC);
    float sum = 0.f;
    for (int k = 0; k < ENC; ++k) sum += W_edge[i * ENC + k] * We[k * ENC + d];
    wcomb[sr * 4 * ENC + i * ENC + d] = sum;
    if (t < ENC) {
      float bs = 0.f;
      for (int k = 0; k < ENC; ++k) bs += b_edge[k] * We[k * ENC + t];
      bcomb[sr * ENC + t] = bs;
    }
  }
}

// ---------------- node encoder: h0 = x @ W_node + b_node (K=8) ----------------
__global__ void k_encode(const float* __restrict__ x, const float* __restrict__ Wn,
                         const float* __restrict__ bn, float* __restrict__ h0) {
  __shared__ float lw[8 * ENC];
  __shared__ float lb[ENC];
  int t = threadIdx.x;
  for (int i = t; i < 8 * ENC; i += blockDim.x) lw[i] = Wn[i];
  if (t < ENC) lb[t] = bn[t];
  __syncthreads();
  int wid = t >> 6, lane = t & 63;
  int nwaves = (blockDim.x >> 6) * gridDim.x;
  int w = blockIdx.x * (blockDim.x >> 6) + wid;
  for (int n = w; n < N_NODES; n += nwaves) {
    const float4* xr4 = (const float4*)(x + n * 8);
    float4 a = xr4[0], b = xr4[1];
    float acc = lb[lane];
    acc += a.x * lw[0 * ENC + lane] + a.y * lw[1 * ENC + lane] +
           a.z * lw[2 * ENC + lane] + a.w * lw[3 * ENC + lane];
    acc += b.x * lw[4 * ENC + lane] + b.y * lw[5 * ENC + lane] +
           b.z * lw[6 * ENC + lane] + b.w * lw[7 * ENC + lane];
    h0[n * ENC + lane] = acc;
  }
}

// ---------------- per-round double GEMM: xl = h@Wl, xr = h@Wr (tiled, no broadcast
// global loads). Block = 256 thr, one 64-node tile. LDS: h-tile 16KB + weights 32KB.
// Lane layout: msel = lane>>5 picks matrix (L/R), cc = lane&31 picks channel pair
// {2cc, 2cc+1}. Weights read as ds_read_b64 (conflict-free: 128 words/wave = 4
// phases, structural minimum); h read as wave-uniform LDS b128 broadcasts,
// amortized over 4-node chunks. ~128 wave-FMA per node -> VALU-limited. ----------
__global__ void __launch_bounds__(256) k_gemm2(const float* __restrict__ hin,
                                               const float* __restrict__ Wl,
                                               const float* __restrict__ Wr,
                                               float* __restrict__ xl,
                                               float* __restrict__ xr) {
  __shared__ float lw[2 * ENC * ENC];  // [mat][k][c]
  __shared__ float lh[64 * ENC];       // [local node][k]
  int t = threadIdx.x;
  {  // stage weights: 2048 float4, fully coalesced
    const float4* wl4 = (const float4*)Wl;
    const float4* wr4 = (const float4*)Wr;
    float4* lw4 = (float4*)lw;
#pragma unroll
    for (int i = 0; i < 4; ++i) lw4[t + 256 * i] = wl4[t + 256 * i];
#pragma unroll
    for (int i = 0; i < 4; ++i) lw4[1024 + t + 256 * i] = wr4[t + 256 * i];
  }
  int base = blockIdx.x * 64;  // first node of tile
  {  // stage h tile: 1024 float4, fully coalesced; clamp OOB to a valid index
    const float4* h4 = (const float4*)hin;
    float4* lh4 = (float4*)lh;
    int maxi = N_NODES * 16 - 1;
#pragma unroll
    for (int i = 0; i < 4; ++i) {
      int idx = t + 256 * i;
      int gi = base * 16 + idx;
      if (gi > maxi) gi = maxi;
      lh4[idx] = h4[gi];
    }
  }
  __syncthreads();
  int wid = t >> 6, lane = t & 63;
  int msel = lane >> 5, cc = lane & 31;
  const float2* lw2 = (const float2*)lw;  // (m,k,cc) at m*2048 + k*32 + cc
  float* outp = msel ? xr : xl;
#pragma unroll
  for (int chunk = 0; chunk < 4; ++chunk) {
    int n0 = wid * 16 + chunk * 4;  // local node of this 4-node chunk
    float a00 = 0.f, a01 = 0.f, a10 = 0.f, a11 = 0.f;
    float a20 = 0.f, a21 = 0.f, a30 = 0.f, a31 = 0.f;
    const float4* r0 = (const float4*)(lh + (n0 + 0) * ENC);
    const float4* r1 = (const float4*)(lh + (n0 + 1) * ENC);
    const float4* r2 = (const float4*)(lh + (n0 + 2) * ENC);
    const float4* r3 = (const float4*)(lh + (n0 + 3) * ENC);
#pragma unroll
    for (int k4 = 0; k4 < 16; ++k4) {
      float4 h0 = r0[k4], h1 = r1[k4], h2 = r2[k4], h3 = r3[k4];
      float2 w0 = lw2[msel * 2048 + (k4 * 4 + 0) * 32 + cc];
      float2 w1 = lw2[msel * 2048 + (k4 * 4 + 1) * 32 + cc];
      float2 w2 = lw2[msel * 2048 + (k4 * 4 + 2) * 32 + cc];
      float2 w3 = lw2[msel * 2048 + (k4 * 4 + 3) * 32 + cc];
      a00 += h0.x * w0.x + h0.y * w1.x + h0.z * w2.x + h0.w * w3.x;
      a01 += h0.x * w0.y + h0.y * w1.y + h0.z * w2.y + h0.w * w3.y;
      a10 += h1.x * w0.x + h1.y * w1.x + h1.z * w2.x + h1.w * w3.x;
      a11 += h1.x * w0.y + h1.y * w1.y + h1.z * w2.y + h1.w * w3.y;
      a20 += h2.x * w0.x + h2.y * w1.x + h2.z * w2.x + h2.w * w3.x;
      a21 += h2.x * w0.y + h2.y * w1.y + h2.z * w2.y + h2.w * w3.y;
      a30 += h3.x * w0.x + h3.y * w1.x + h3.z * w2.x + h3.w * w3.x;
      a31 += h3.x * w0.y + h3.y * w1.y + h3.z * w2.y + h3.w * w3.y;
    }
    int ng = base + n0;
    if (ng + 0 < N_NODES) *(float2*)(outp + (size_t)(ng + 0) * ENC + cc * 2) = make_float2(a00, a01);
    if (ng + 1 < N_NODES) *(float2*)(outp + (size_t)(ng + 1) * ENC + cc * 2) = make_float2(a10, a11);
    if (ng + 2 < N_NODES) *(float2*)(outp + (size_t)(ng + 2) * ENC + cc * 2) = make_float2(a20, a21);
    if (ng + 3 < N_NODES) *(float2*)(outp + (size_t)(ng + 3) * ENC + cc * 2) = make_float2(a30, a31);
  }
}

// ---------------- edge scores: s[e] = att . lrelu(xl[src]+xr[dst]+ea@Wc+bc) ----
__global__ void k_score(const float* __restrict__ xl, const float* __restrict__ xr,
                        const float* __restrict__ ea, const int* __restrict__ src,
                        const int* __restrict__ dst, const float* __restrict__ wc,
                        const float* __restrict__ bc, const float* __restrict__ att,
                        float* __restrict__ s, u32* __restrict__ smax) {
  __shared__ float lwc[4 * ENC];
  __shared__ float lbc[ENC];
  __shared__ float latt[ENC];
  int t = threadIdx.x;
  for (int i = t; i < 4 * ENC; i += blockDim.x) lwc[i] = wc[i];
  if (t < ENC) {
    lbc[t] = bc[t];
    latt[t] = att[t];
  }
  __syncthreads();
  int g = t >> 4, sub = t & 15;
  int gpb = blockDim.x >> 4;
  int e0 = blockIdx.x * gpb + g, stride = gridDim.x * gpb;
  int c = sub * 4;
  for (int e = e0; e < N_EDGES; e += stride) {
    int sn = src[e], dn = dst[e];
    float4 av = ((const float4*)ea)[e];
    float4 lv = ((const float4*)xl)[sn * 16 + sub];
    float4 rv = ((const float4*)xr)[dn * 16 + sub];
    float m0 = lv.x + rv.x + lbc[c + 0] + av.x * lwc[0 * ENC + c + 0] + av.y * lwc[1 * ENC + c + 0] + av.z * lwc[2 * ENC + c + 0] + av.w * lwc[3 * ENC + c + 0];
    float m1 = lv.y + rv.y + lbc[c + 1] + av.x * lwc[0 * ENC + c + 1] + av.y * lwc[1 * ENC + c + 1] + av.z * lwc[2 * ENC + c + 1] + av.w * lwc[3 * ENC + c + 1];
    float m2 = lv.z + rv.z + lbc[c + 2] + av.x * lwc[0 * ENC + c + 2] + av.y * lwc[1 * ENC + c + 2] + av.z * lwc[2 * ENC + c + 2] + av.w * lwc[3 * ENC + c + 2];
    float m3 = lv.w + rv.w + lbc[c + 3] + av.x * lwc[0 * ENC + c + 3] + av.y * lwc[1 * ENC + c + 3] + av.z * lwc[2 * ENC + c + 3] + av.w * lwc[3 * ENC + c + 3];
    float p = lrelu(m0) * latt[c + 0] + lrelu(m1) * latt[c + 1] +
              lrelu(m2) * latt[c + 2] + lrelu(m3) * latt[c + 3];
    p += __shfl_xor(p, 1);
    p += __shfl_xor(p, 2);
    p += __shfl_xor(p, 4);
    p += __shfl_xor(p, 8);
    if (sub == 0) {
      s[e] = p;
      atomicMax(&smax[dn], ford(p));
    }
  }
}

// ---------------- per-dst softmax + weighted aggregate (one wave per node) ----
template <int RELU>
__global__ void k_aggr(const int* __restrict__ row_start, const int* __restrict__ eid,
                       const int* __restrict__ srcs, const float* __restrict__ s,
                       const u32* __restrict__ smax, const float* __restrict__ xl,
                       const float* __restrict__ b, float* __restrict__ hout) {
  int t = threadIdx.x;
  int wid = t >> 6, lane = t & 63;
  int nw = (blockDim.x >> 6) * gridDim.x;
  int w = blockIdx.x * (blockDim.x >> 6) + wid;
  for (int n = w; n < N_NODES; n += nw) {
    int rs = row_start[n], re = row_start[n + 1];
    float bv = b[lane];
    float outv;
    if (re > rs) {
      float mx = funord(smax[n]);
      float acc = 0.f, den = 0.f;
      for (int i = rs; i < re; ++i) {
        int e = eid[i];
        int sn = srcs[i];
        float ex = __expf(s[e] - mx);
        den += ex;
        acc += ex * xl[sn * ENC + lane];
      }
      outv = acc / den + bv;
    } else {
      outv = bv;  // empty neighborhood: segment sums are 0, out = b
    }
    if (RELU) outv = fmaxf(outv, 0.f);
    hout[n * ENC + lane] = outv;
  }
}

// ---------------- decoders ----------------
__global__ void k_act(const float* __restrict__ ha, const float* __restrict__ Wa,
                      const float* __restrict__ ba, float* __restrict__ out) {
  int t = threadIdx.x;
  int wid = t >> 6, lane = t & 63;
  int nw = (blockDim.x >> 6) * gridDim.x;
  int w = blockIdx.x * (blockDim.x >> 6) + wid;
  for (int n = w; n < N_NODES; n += nw) {
    float hv = ha[n * ENC + lane];
#pragma unroll
    for (int j = 0; j < 5; ++j) {
      float p = hv * Wa[lane * 5 + j];
      p += __shfl_xor(p, 1);
      p += __shfl_xor(p, 2);
      p += __shfl_xor(p, 4);
      p += __shfl_xor(p, 8);
      p += __shfl_xor(p, 16);
      p += __shfl_xor(p, 32);
      if (lane == 0) out[n * 6 + j] = tanhf(p + ba[j]);
    }
  }
}

__global__ void k_val(const float* __restrict__ hc, const float* __restrict__ Wv,
                      const float* __restrict__ bv, float* __restrict__ out) {
  int t = threadIdx.x;
  int wid = t >> 6, lane = t & 63;
  int nw = (blockDim.x >> 6) * gridDim.x;
  int w = blockIdx.x * (blockDim.x >> 6) + wid;
  for (int n = w; n < N_NODES; n += nw) {
    float p = hc[n * ENC + lane] * Wv[lane];
    p += __shfl_xor(p, 1);
    p += __shfl_xor(p, 2);
    p += __shfl_xor(p, 4);
    p += __shfl_xor(p, 8);
    p += __shfl_xor(p, 16);
    p += __shfl_xor(p, 32);
    if (lane == 0) out[n * 6 + 5] = p + bv[0];
  }
}

extern "C" void kernel_launch(void* const* d_in, const int* in_sizes, int n_in,
                              void* d_out, int out_size, void* d_ws, size_t ws_size,
                              hipStream_t stream) {
  const float* x    = (const float*)d_in[0];
  const float* ea   = (const float*)d_in[1];
  const float* Wn   = (const float*)d_in[2];
  const float* bn   = (const float*)d_in[3];
  const float* Wedg = (const float*)d_in[4];
  const float* bedg = (const float*)d_in[5];
  const float* aWl  = (const float*)d_in[6];
  const float* aWr  = (const float*)d_in[7];
  const float* aWe  = (const float*)d_in[8];
  const float* aAtt = (const float*)d_in[9];
  const float* aB   = (const float*)d_in[10];
  const float* cWl  = (const float*)d_in[11];
  const float* cWr  = (const float*)d_in[12];
  const float* cWe  = (const float*)d_in[13];
  const float* cAtt = (const float*)d_in[14];
  const float* cB   = (const float*)d_in[15];
  const float* Wa   = (const float*)d_in[16];
  const float* ba   = (const float*)d_in[17];
  const float* Wv   = (const float*)d_in[18];
  const float* bv   = (const float*)d_in[19];
  const int* src    = (const int*)d_in[20];
  const int* dst    = (const int*)d_in[21];
  float* out = (float*)d_out;

  char* w = (char*)d_ws;
  size_t off = 0;
  auto alloc = [&](size_t bytes) -> char* {
    char* p = w + off;
    off = (off + bytes + 255) & ~(size_t)255;
    return p;
  };
  float* h0 = (float*)alloc((size_t)N_NODES * ENC * 4);
  float* h  = (float*)alloc((size_t)N_NODES * ENC * 4);
  float* xl = (float*)alloc((size_t)N_NODES * ENC * 4);
  float* xr = (float*)alloc((size_t)N_NODES * ENC * 4);
  float* s  = (float*)alloc((size_t)N_EDGES * 4);
  int* eid  = (int*)alloc((size_t)N_EDGES * 4);
  int* srcs = (int*)alloc((size_t)N_EDGES * 4);
  int* row_start = (int*)alloc((size_t)(N_NODES + 1) * 4);
  int* cursor    = (int*)alloc((size_t)N_NODES * 4);
  u32* smax      = (u32*)alloc((size_t)N_NODES * 4);
  float* wcomb   = (float*)alloc(6 * 4 * ENC * 4);
  float* bcomb   = (float*)alloc(6 * ENC * 4);

  // ---- CSR build (per-launch, deterministic up to fp-neutral edge order) ----
  hipMemsetAsync(cursor, 0, (size_t)N_NODES * 4, stream);
  k_hist<<<2048, 256, 0, stream>>>(dst, cursor);
  k_scan<<<1, 1024, 0, stream>>>(cursor, row_start);
  k_scatter<<<2048, 256, 0, stream>>>(src, dst, cursor, eid, srcs);

  // ---- folded edge weights + encoder ----
  k_wcomb<<<1, 256, 0, stream>>>(Wedg, bedg, aWe, cWe, wcomb, bcomb);
  k_encode<<<512, 256, 0, stream>>>(x, Wn, bn, h0);

  const int GEMM_TILES = (N_NODES + 63) / 64;  // 782

  for (int st = 0; st < 2; ++st) {
    const float* Wl = st ? cWl : aWl;
    const float* Wr = st ? cWr : aWr;
    const float* At = st ? cAtt : aAtt;
    const float* B  = st ? cB : aB;
    for (int r = 0; r < ROUNDS; ++r) {
      const float* hin = (r == 0) ? h0 : h;
      k_gemm2<<<GEMM_TILES, 256, 0, stream>>>(hin, Wl + r * ENC * ENC, Wr + r * ENC * ENC, xl, xr);
      hipMemsetAsync(smax, 0, (size_t)N_NODES * 4, stream);
      k_score<<<4096, 256, 0, stream>>>(xl, xr, ea, src, dst,
                                        wcomb + (st * 3 + r) * 4 * ENC,
                                        bcomb + (st * 3 + r) * ENC,
                                        At + r * ENC, s, smax);
      if (r < ROUNDS - 1)
        k_aggr<1><<<2048, 256, 0, stream>>>(row_start, eid, srcs, s, smax, xl, B + r * ENC, h);
      else
        k_aggr<0><<<2048, 256, 0, stream>>>(row_start, eid, srcs, s, smax, xl, B + r * ENC, h);
    }
    if (st == 0)
      k_act<<<1024, 256, 0, stream>>>(h, Wa, ba, out);
    else
      k_val<<<1024, 256, 0, stream>>>(h, Wv, bv, out);
  }
}

// Round 3
// 1041.880 us; speedup vs baseline: 3.4141x; 1.4645x over previous
//
#include <hip/hip_runtime.h>
#include <math.h>

#define N_NODES 50000
#define N_EDGES 800000
#define ENC 64
#define ROUNDS 3
#define NEG_SLOPE 0.2f

typedef unsigned int u32;

__device__ __forceinline__ float lrelu(float m) {
  return m > 0.f ? m : NEG_SLOPE * m;
}

// ---------------- CSR build ----------------
__global__ void k_hist(const int* __restrict__ dst, int* __restrict__ deg) {
  int i = blockIdx.x * blockDim.x + threadIdx.x;
  int stride = gridDim.x * blockDim.x;
  for (; i < N_EDGES; i += stride) atomicAdd(&deg[dst[i]], 1);
}

#define SCAN_BLOCKS ((N_NODES + 255) / 256)  // 196

__global__ void __launch_bounds__(256) k_red(const int* __restrict__ deg,
                                             int* __restrict__ part) {
  __shared__ int sm[256];
  int bi = blockIdx.x, t = threadIdx.x;
  int i = bi * 256 + t;
  sm[t] = (i < N_NODES) ? deg[i] : 0;
  __syncthreads();
  for (int off = 128; off > 0; off >>= 1) {
    if (t < off) sm[t] += sm[t + off];
    __syncthreads();
  }
  if (t == 0) part[bi] = sm[0];
}

__global__ void __launch_bounds__(256) k_scanp(int* __restrict__ part) {
  __shared__ int sm[256];
  int t = threadIdx.x;
  int v = (t < SCAN_BLOCKS) ? part[t] : 0;
  sm[t] = v;
  __syncthreads();
  for (int off = 1; off < 256; off <<= 1) {
    int u = (t >= off) ? sm[t - off] : 0;
    __syncthreads();
    sm[t] += u;
    __syncthreads();
  }
  if (t < SCAN_BLOCKS) part[t] = sm[t] - v;  // exclusive
}

// degcur: degrees on entry, scatter cursors (= row_start) on exit.
__global__ void __launch_bounds__(256) k_csr(int* __restrict__ degcur,
                                             const int* __restrict__ part,
                                             int* __restrict__ row_start) {
  __shared__ int sm[256];
  int bi = blockIdx.x, t = threadIdx.x;
  int i = bi * 256 + t;
  int v = (i < N_NODES) ? degcur[i] : 0;
  sm[t] = v;
  __syncthreads();
  for (int off = 1; off < 256; off <<= 1) {
    int u = (t >= off) ? sm[t - off] : 0;
    __syncthreads();
    sm[t] += u;
    __syncthreads();
  }
  int excl = sm[t] - v + part[bi];
  if (i < N_NODES) {
    row_start[i] = excl;
    degcur[i] = excl;
    if (i == N_NODES - 1) row_start[N_NODES] = excl + v;
  }
}

// scatter edges into CSR order; also permute edge_attr so the fused kernel
// reads it coalesced (ea_perm[pos] = ea[e]).
__global__ void k_scatter(const int* __restrict__ src, const int* __restrict__ dst,
                          const float* __restrict__ ea, int* __restrict__ cursor,
                          int* __restrict__ srcs, float* __restrict__ ea_perm) {
  int i = blockIdx.x * blockDim.x + threadIdx.x;
  int stride = gridDim.x * blockDim.x;
  for (; i < N_EDGES; i += stride) {
    int d = dst[i];
    int pos = atomicAdd(&cursor[d], 1);
    srcs[pos] = src[i];
    ((float4*)ea_perm)[pos] = ((const float4*)ea)[i];
  }
}

// ---------------- tiny weight fold: W_comb = W_edge @ We, b_comb = b_edge @ We ----
__global__ void k_wcomb(const float* __restrict__ W_edge, const float* __restrict__ b_edge,
                        const float* __restrict__ aWe, const float* __restrict__ cWe,
                        float* __restrict__ wcomb, float* __restrict__ bcomb) {
  int t = threadIdx.x;  // 256
  int i = t >> 6, d = t & 63;
  for (int sr = 0; sr < 6; ++sr) {
    const float* We = (sr < 3) ? (aWe + sr * ENC * ENC) : (cWe + (sr - 3) * ENC * ENC);
    float sum = 0.f;
    for (int k = 0; k < ENC; ++k) sum += W_edge[i * ENC + k] * We[k * ENC + d];
    wcomb[sr * 4 * ENC + i * ENC + d] = sum;
    if (t < ENC) {
      float bs = 0.f;
      for (int k = 0; k < ENC; ++k) bs += b_edge[k] * We[k * ENC + t];
      bcomb[sr * ENC + t] = bs;
    }
  }
}

// ---------------- node encoder: h0 = x @ W_node + b_node (K=8) ----------------
__global__ void k_encode(const float* __restrict__ x, const float* __restrict__ Wn,
                         const float* __restrict__ bn, float* __restrict__ h0) {
  __shared__ float lw[8 * ENC];
  __shared__ float lb[ENC];
  int t = threadIdx.x;
  for (int i = t; i < 8 * ENC; i += blockDim.x) lw[i] = Wn[i];
  if (t < ENC) lb[t] = bn[t];
  __syncthreads();
  int wid = t >> 6, lane = t & 63;
  int nwaves = (blockDim.x >> 6) * gridDim.x;
  int w = blockIdx.x * (blockDim.x >> 6) + wid;
  for (int n = w; n < N_NODES; n += nwaves) {
    const float4* xr4 = (const float4*)(x + n * 8);
    float4 a = xr4[0], b = xr4[1];
    float acc = lb[lane];
    acc += a.x * lw[0 * ENC + lane] + a.y * lw[1 * ENC + lane] +
           a.z * lw[2 * ENC + lane] + a.w * lw[3 * ENC + lane];
    acc += b.x * lw[4 * ENC + lane] + b.y * lw[5 * ENC + lane] +
           b.z * lw[6 * ENC + lane] + b.w * lw[7 * ENC + lane];
    h0[n * ENC + lane] = acc;
  }
}

// ---------------- per-round double GEMM: xl = h@Wl, xr = h@Wr + bcomb ----------
__global__ void __launch_bounds__(256) k_gemm2(const float* __restrict__ hin,
                                               const float* __restrict__ Wl,
                                               const float* __restrict__ Wr,
                                               const float* __restrict__ bc,
                                               float* __restrict__ xl,
                                               float* __restrict__ xr) {
  __shared__ float lw[2 * ENC * ENC];  // [mat][k][c]
  __shared__ float lh[64 * ENC];       // [local node][k]
  int t = threadIdx.x;
  {  // stage weights: 2048 float4, fully coalesced
    const float4* wl4 = (const float4*)Wl;
    const float4* wr4 = (const float4*)Wr;
    float4* lw4 = (float4*)lw;
#pragma unroll
    for (int i = 0; i < 4; ++i) lw4[t + 256 * i] = wl4[t + 256 * i];
#pragma unroll
    for (int i = 0; i < 4; ++i) lw4[1024 + t + 256 * i] = wr4[t + 256 * i];
  }
  int base = blockIdx.x * 64;  // first node of tile
  {  // stage h tile: 1024 float4, fully coalesced; clamp OOB to a valid index
    const float4* h4 = (const float4*)hin;
    float4* lh4 = (float4*)lh;
    int maxi = N_NODES * 16 - 1;
#pragma unroll
    for (int i = 0; i < 4; ++i) {
      int idx = t + 256 * i;
      int gi = base * 16 + idx;
      if (gi > maxi) gi = maxi;
      lh4[idx] = h4[gi];
    }
  }
  __syncthreads();
  int wid = t >> 6, lane = t & 63;
  int msel = lane >> 5, cc = lane & 31;
  const float2* lw2 = (const float2*)lw;  // (m,k,cc) at m*2048 + k*32 + cc
  float* outp = msel ? xr : xl;
  float2 bcv = make_float2(0.f, 0.f);
  if (msel) bcv = ((const float2*)bc)[cc];  // fold edge-encoder bias into xr
#pragma unroll
  for (int chunk = 0; chunk < 4; ++chunk) {
    int n0 = wid * 16 + chunk * 4;  // local node of this 4-node chunk
    float a00 = 0.f, a01 = 0.f, a10 = 0.f, a11 = 0.f;
    float a20 = 0.f, a21 = 0.f, a30 = 0.f, a31 = 0.f;
    const float4* r0 = (const float4*)(lh + (n0 + 0) * ENC);
    const float4* r1 = (const float4*)(lh + (n0 + 1) * ENC);
    const float4* r2 = (const float4*)(lh + (n0 + 2) * ENC);
    const float4* r3 = (const float4*)(lh + (n0 + 3) * ENC);
#pragma unroll
    for (int k4 = 0; k4 < 16; ++k4) {
      float4 h0 = r0[k4], h1 = r1[k4], h2 = r2[k4], h3 = r3[k4];
      float2 w0 = lw2[msel * 2048 + (k4 * 4 + 0) * 32 + cc];
      float2 w1 = lw2[msel * 2048 + (k4 * 4 + 1) * 32 + cc];
      float2 w2 = lw2[msel * 2048 + (k4 * 4 + 2) * 32 + cc];
      float2 w3 = lw2[msel * 2048 + (k4 * 4 + 3) * 32 + cc];
      a00 += h0.x * w0.x + h0.y * w1.x + h0.z * w2.x + h0.w * w3.x;
      a01 += h0.x * w0.y + h0.y * w1.y + h0.z * w2.y + h0.w * w3.y;
      a10 += h1.x * w0.x + h1.y * w1.x + h1.z * w2.x + h1.w * w3.x;
      a11 += h1.x * w0.y + h1.y * w1.y + h1.z * w2.y + h1.w * w3.y;
      a20 += h2.x * w0.x + h2.y * w1.x + h2.z * w2.x + h2.w * w3.x;
      a21 += h2.x * w0.y + h2.y * w1.y + h2.z * w2.y + h2.w * w3.y;
      a30 += h3.x * w0.x + h3.y * w1.x + h3.z * w2.x + h3.w * w3.x;
      a31 += h3.x * w0.y + h3.y * w1.y + h3.z * w2.y + h3.w * w3.y;
    }
    int ng = base + n0;
    if (ng + 0 < N_NODES) *(float2*)(outp + (size_t)(ng + 0) * ENC + cc * 2) = make_float2(a00 + bcv.x, a01 + bcv.y);
    if (ng + 1 < N_NODES) *(float2*)(outp + (size_t)(ng + 1) * ENC + cc * 2) = make_float2(a10 + bcv.x, a11 + bcv.y);
    if (ng + 2 < N_NODES) *(float2*)(outp + (size_t)(ng + 2) * ENC + cc * 2) = make_float2(a20 + bcv.x, a21 + bcv.y);
    if (ng + 3 < N_NODES) *(float2*)(outp + (size_t)(ng + 3) * ENC + cc * 2) = make_float2(a30 + bcv.x, a31 + bcv.y);
  }
}

// ---------------- fused score + online softmax + aggregate, both stacks -------
// wave = dst node, lane = channel. Per edge: gather xl_a/xl_c rows (coalesced
// 256B), ea/srcs read coalesced in CSR chunks and broadcast via shfl (NEVER
// wave-uniform vector loads - 64x amplification, round-1 lesson). Online
// max-tracked softmax; wave-uniform control flow throughout.
template <int RELU>
__global__ void k_attn(const int* __restrict__ row_start, const int* __restrict__ srcs,
                       const float* __restrict__ ea_perm,
                       const float* __restrict__ xla, const float* __restrict__ xra,
                       const float* __restrict__ xlc, const float* __restrict__ xrc,
                       const float* __restrict__ wca, const float* __restrict__ wcc,
                       const float* __restrict__ atta, const float* __restrict__ attc,
                       const float* __restrict__ Ba, const float* __restrict__ Bc,
                       float* __restrict__ ha, float* __restrict__ hc) {
  int t = threadIdx.x;
  int wid = t >> 6, lane = t & 63;
  // per-lane (channel) constants
  float wa0 = wca[0 * ENC + lane], wa1 = wca[1 * ENC + lane];
  float wa2 = wca[2 * ENC + lane], wa3 = wca[3 * ENC + lane];
  float wc0 = wcc[0 * ENC + lane], wc1 = wcc[1 * ENC + lane];
  float wc2 = wcc[2 * ENC + lane], wc3 = wcc[3 * ENC + lane];
  float ata = atta[lane], atc = attc[lane];
  float bva = Ba[lane], bvc = Bc[lane];
  int nw = (blockDim.x >> 6) * gridDim.x;
  for (int n = blockIdx.x * (blockDim.x >> 6) + wid; n < N_NODES; n += nw) {
    int rs = row_start[n], re = row_start[n + 1];
    float outa, outc;
    if (re > rs) {
      float xran = xra[(size_t)n * ENC + lane];
      float xrcn = xrc[(size_t)n * ENC + lane];
      float ma = -1e30f, mc = -1e30f;
      float dena = 0.f, denc = 0.f, acca = 0.f, accc = 0.f;
      for (int base = rs; base < re; base += 16) {
        int cnt = re - base;
        if (cnt > 16) cnt = 16;
        // cooperative coalesced chunk loads, lane-distributed
        float eav = (lane < 4 * cnt) ? ea_perm[(size_t)base * 4 + lane] : 0.f;
        int sval = (lane < cnt) ? srcs[base + lane] : 0;
#pragma unroll
        for (int jj = 0; jj < 16; ++jj) {
          if (jj >= cnt) break;  // wave-uniform
          int sn = __shfl(sval, jj);
          float av0 = __shfl(eav, jj * 4 + 0);
          float av1 = __shfl(eav, jj * 4 + 1);
          float av2 = __shfl(eav, jj * 4 + 2);
          float av3 = __shfl(eav, jj * 4 + 3);
          float la = xla[(size_t)sn * ENC + lane];
          float lc = xlc[(size_t)sn * ENC + lane];
          float mma = la + xran + av0 * wa0 + av1 * wa1 + av2 * wa2 + av3 * wa3;
          float mmc = lc + xrcn + av0 * wc0 + av1 * wc1 + av2 * wc2 + av3 * wc3;
          float pa = lrelu(mma) * ata;
          float pc = lrelu(mmc) * atc;
          // full-wave reductions -> wave-uniform scores
          pa += __shfl_xor(pa, 1);  pc += __shfl_xor(pc, 1);
          pa += __shfl_xor(pa, 2);  pc += __shfl_xor(pc, 2);
          pa += __shfl_xor(pa, 4);  pc += __shfl_xor(pc, 4);
          pa += __shfl_xor(pa, 8);  pc += __shfl_xor(pc, 8);
          pa += __shfl_xor(pa, 16); pc += __shfl_xor(pc, 16);
          pa += __shfl_xor(pa, 32); pc += __shfl_xor(pc, 32);
          // online softmax update (branchless, wave-uniform scalars)
          float mna = fmaxf(ma, pa);
          float sca = __expf(ma - mna);
          float exa = __expf(pa - mna);
          dena = dena * sca + exa;
          acca = acca * sca + exa * la;
          ma = mna;
          float mnc = fmaxf(mc, pc);
          float scc = __expf(mc - mnc);
          float exc = __expf(pc - mnc);
          denc = denc * scc + exc;
          accc = accc * scc + exc * lc;
          mc = mnc;
        }
      }
      outa = acca / dena + bva;
      outc = accc / denc + bvc;
    } else {
      outa = bva;
      outc = bvc;
    }
    if (RELU) {
      outa = fmaxf(outa, 0.f);
      outc = fmaxf(outc, 0.f);
    }
    ha[(size_t)n * ENC + lane] = outa;
    hc[(size_t)n * ENC + lane] = outc;
  }
}

// ---------------- decoders ----------------
__global__ void k_act(const float* __restrict__ ha, const float* __restrict__ Wa,
                      const float* __restrict__ ba, float* __restrict__ out) {
  int t = threadIdx.x;
  int wid = t >> 6, lane = t & 63;
  int nw = (blockDim.x >> 6) * gridDim.x;
  int w = blockIdx.x * (blockDim.x >> 6) + wid;
  for (int n = w; n < N_NODES; n += nw) {
    float hv = ha[n * ENC + lane];
#pragma unroll
    for (int j = 0; j < 5; ++j) {
      float p = hv * Wa[lane * 5 + j];
      p += __shfl_xor(p, 1);
      p += __shfl_xor(p, 2);
      p += __shfl_xor(p, 4);
      p += __shfl_xor(p, 8);
      p += __shfl_xor(p, 16);
      p += __shfl_xor(p, 32);
      if (lane == 0) out[n * 6 + j] = tanhf(p + ba[j]);
    }
  }
}

__global__ void k_val(const float* __restrict__ hc, const float* __restrict__ Wv,
                      const float* __restrict__ bv, float* __restrict__ out) {
  int t = threadIdx.x;
  int wid = t >> 6, lane = t & 63;
  int nw = (blockDim.x >> 6) * gridDim.x;
  int w = blockIdx.x * (blockDim.x >> 6) + wid;
  for (int n = w; n < N_NODES; n += nw) {
    float p = hc[n * ENC + lane] * Wv[lane];
    p += __shfl_xor(p, 1);
    p += __shfl_xor(p, 2);
    p += __shfl_xor(p, 4);
    p += __shfl_xor(p, 8);
    p += __shfl_xor(p, 16);
    p += __shfl_xor(p, 32);
    if (lane == 0) out[n * 6 + 5] = p + bv[0];
  }
}

extern "C" void kernel_launch(void* const* d_in, const int* in_sizes, int n_in,
                              void* d_out, int out_size, void* d_ws, size_t ws_size,
                              hipStream_t stream) {
  const float* x    = (const float*)d_in[0];
  const float* ea   = (const float*)d_in[1];
  const float* Wn   = (const float*)d_in[2];
  const float* bn   = (const float*)d_in[3];
  const float* Wedg = (const float*)d_in[4];
  const float* bedg = (const float*)d_in[5];
  const float* aWl  = (const float*)d_in[6];
  const float* aWr  = (const float*)d_in[7];
  const float* aWe  = (const float*)d_in[8];
  const float* aAtt = (const float*)d_in[9];
  const float* aB   = (const float*)d_in[10];
  const float* cWl  = (const float*)d_in[11];
  const float* cWr  = (const float*)d_in[12];
  const float* cWe  = (const float*)d_in[13];
  const float* cAtt = (const float*)d_in[14];
  const float* cB   = (const float*)d_in[15];
  const float* Wa   = (const float*)d_in[16];
  const float* ba   = (const float*)d_in[17];
  const float* Wv   = (const float*)d_in[18];
  const float* bv   = (const float*)d_in[19];
  const int* src    = (const int*)d_in[20];
  const int* dst    = (const int*)d_in[21];
  float* out = (float*)d_out;

  char* w = (char*)d_ws;
  size_t off = 0;
  auto alloc = [&](size_t bytes) -> char* {
    char* p = w + off;
    off = (off + bytes + 255) & ~(size_t)255;
    return p;
  };
  float* h0  = (float*)alloc((size_t)N_NODES * ENC * 4);
  float* hA  = (float*)alloc((size_t)N_NODES * ENC * 4);
  float* hC  = (float*)alloc((size_t)N_NODES * ENC * 4);
  float* xlA = (float*)alloc((size_t)N_NODES * ENC * 4);
  float* xrA = (float*)alloc((size_t)N_NODES * ENC * 4);
  float* xlC = (float*)alloc((size_t)N_NODES * ENC * 4);
  float* xrC = (float*)alloc((size_t)N_NODES * ENC * 4);
  int* srcs      = (int*)alloc((size_t)N_EDGES * 4);
  float* ea_perm = (float*)alloc((size_t)N_EDGES * 16);
  int* row_start = (int*)alloc((size_t)(N_NODES + 1) * 4);
  int* cursor    = (int*)alloc((size_t)N_NODES * 4);
  int* part      = (int*)alloc(256 * 4);
  float* wcomb   = (float*)alloc(6 * 4 * ENC * 4);
  float* bcomb   = (float*)alloc(6 * ENC * 4);

  // ---- CSR build ----
  hipMemsetAsync(cursor, 0, (size_t)N_NODES * 4, stream);
  k_hist<<<2048, 256, 0, stream>>>(dst, cursor);
  k_red<<<SCAN_BLOCKS, 256, 0, stream>>>(cursor, part);
  k_scanp<<<1, 256, 0, stream>>>(part);
  k_csr<<<SCAN_BLOCKS, 256, 0, stream>>>(cursor, part, row_start);
  k_scatter<<<2048, 256, 0, stream>>>(src, dst, ea, cursor, srcs, ea_perm);

  // ---- folded edge weights + encoder ----
  k_wcomb<<<1, 256, 0, stream>>>(Wedg, bedg, aWe, cWe, wcomb, bcomb);
  k_encode<<<512, 256, 0, stream>>>(x, Wn, bn, h0);

  const int GEMM_TILES = (N_NODES + 63) / 64;  // 782

  for (int r = 0; r < ROUNDS; ++r) {
    const float* hinA = (r == 0) ? h0 : hA;
    const float* hinC = (r == 0) ? h0 : hC;
    k_gemm2<<<GEMM_TILES, 256, 0, stream>>>(hinA, aWl + r * ENC * ENC, aWr + r * ENC * ENC,
                                            bcomb + r * ENC, xlA, xrA);
    k_gemm2<<<GEMM_TILES, 256, 0, stream>>>(hinC, cWl + r * ENC * ENC, cWr + r * ENC * ENC,
                                            bcomb + (3 + r) * ENC, xlC, xrC);
    if (r < ROUNDS - 1)
      k_attn<1><<<2048, 256, 0, stream>>>(row_start, srcs, ea_perm, xlA, xrA, xlC, xrC,
                                          wcomb + r * 4 * ENC, wcomb + (3 + r) * 4 * ENC,
                                          aAtt + r * ENC, cAtt + r * ENC,
                                          aB + r * ENC, cB + r * ENC, hA, hC);
    else
      k_attn<0><<<2048, 256, 0, stream>>>(row_start, srcs, ea_perm, xlA, xrA, xlC, xrC,
                                          wcomb + r * 4 * ENC, wcomb + (3 + r) * 4 * ENC,
                                          aAtt + r * ENC, cAtt + r * ENC,
                                          aB + r * ENC, cB + r * ENC, hA, hC);
  }
  k_act<<<1024, 256, 0, stream>>>(hA, Wa, ba, out);
  k_val<<<1024, 256, 0, stream>>>(hC, Wv, bv, out);
}

// Round 4
// 787.610 us; speedup vs baseline: 4.5162x; 1.3228x over previous
//
#include <hip/hip_runtime.h>
#include <math.h>

#define N_NODES 50000
#define N_EDGES 800000
#define ENC 64
#define ROUNDS 3
#define NEG_SLOPE 0.2f

typedef unsigned int u32;

__device__ __forceinline__ float lrelu(float m) {
  return m > 0.f ? m : NEG_SLOPE * m;
}

// ---------------- CSR build ----------------
__global__ void k_hist(const int* __restrict__ dst, int* __restrict__ deg) {
  int i = blockIdx.x * blockDim.x + threadIdx.x;
  int stride = gridDim.x * blockDim.x;
  for (; i < N_EDGES; i += stride) atomicAdd(&deg[dst[i]], 1);
}

#define SCAN_BLOCKS ((N_NODES + 255) / 256)  // 196

__global__ void __launch_bounds__(256) k_red(const int* __restrict__ deg,
                                             int* __restrict__ part) {
  __shared__ int sm[256];
  int bi = blockIdx.x, t = threadIdx.x;
  int i = bi * 256 + t;
  sm[t] = (i < N_NODES) ? deg[i] : 0;
  __syncthreads();
  for (int off = 128; off > 0; off >>= 1) {
    if (t < off) sm[t] += sm[t + off];
    __syncthreads();
  }
  if (t == 0) part[bi] = sm[0];
}

__global__ void __launch_bounds__(256) k_scanp(int* __restrict__ part) {
  __shared__ int sm[256];
  int t = threadIdx.x;
  int v = (t < SCAN_BLOCKS) ? part[t] : 0;
  sm[t] = v;
  __syncthreads();
  for (int off = 1; off < 256; off <<= 1) {
    int u = (t >= off) ? sm[t - off] : 0;
    __syncthreads();
    sm[t] += u;
    __syncthreads();
  }
  if (t < SCAN_BLOCKS) part[t] = sm[t] - v;  // exclusive
}

// degcur: degrees on entry, scatter cursors (= row_start) on exit.
__global__ void __launch_bounds__(256) k_csr(int* __restrict__ degcur,
                                             const int* __restrict__ part,
                                             int* __restrict__ row_start) {
  __shared__ int sm[256];
  int bi = blockIdx.x, t = threadIdx.x;
  int i = bi * 256 + t;
  int v = (i < N_NODES) ? degcur[i] : 0;
  sm[t] = v;
  __syncthreads();
  for (int off = 1; off < 256; off <<= 1) {
    int u = (t >= off) ? sm[t - off] : 0;
    __syncthreads();
    sm[t] += u;
    __syncthreads();
  }
  int excl = sm[t] - v + part[bi];
  if (i < N_NODES) {
    row_start[i] = excl;
    degcur[i] = excl;
    if (i == N_NODES - 1) row_start[N_NODES] = excl + v;
  }
}

// scatter edges into CSR order; also permute edge_attr so the fused kernel
// reads it coalesced (ea_perm[pos] = ea[e]).
__global__ void k_scatter(const int* __restrict__ src, const int* __restrict__ dst,
                          const float* __restrict__ ea, int* __restrict__ cursor,
                          int* __restrict__ srcs, float* __restrict__ ea_perm) {
  int i = blockIdx.x * blockDim.x + threadIdx.x;
  int stride = gridDim.x * blockDim.x;
  for (; i < N_EDGES; i += stride) {
    int d = dst[i];
    int pos = atomicAdd(&cursor[d], 1);
    srcs[pos] = src[i];
    ((float4*)ea_perm)[pos] = ((const float4*)ea)[i];
  }
}

// ---------------- tiny weight fold: W_comb = W_edge @ We, b_comb = b_edge @ We ----
__global__ void k_wcomb(const float* __restrict__ W_edge, const float* __restrict__ b_edge,
                        const float* __restrict__ aWe, const float* __restrict__ cWe,
                        float* __restrict__ wcomb, float* __restrict__ bcomb) {
  int t = threadIdx.x;  // 256
  int i = t >> 6, d = t & 63;
  for (int sr = 0; sr < 6; ++sr) {
    const float* We = (sr < 3) ? (aWe + sr * ENC * ENC) : (cWe + (sr - 3) * ENC * ENC);
    float sum = 0.f;
    for (int k = 0; k < ENC; ++k) sum += W_edge[i * ENC + k] * We[k * ENC + d];
    wcomb[sr * 4 * ENC + i * ENC + d] = sum;
    if (t < ENC) {
      float bs = 0.f;
      for (int k = 0; k < ENC; ++k) bs += b_edge[k] * We[k * ENC + t];
      bcomb[sr * ENC + t] = bs;
    }
  }
}

// ---------------- node encoder: h0 = x @ W_node + b_node (K=8) ----------------
__global__ void k_encode(const float* __restrict__ x, const float* __restrict__ Wn,
                         const float* __restrict__ bn, float* __restrict__ h0) {
  __shared__ float lw[8 * ENC];
  __shared__ float lb[ENC];
  int t = threadIdx.x;
  for (int i = t; i < 8 * ENC; i += blockDim.x) lw[i] = Wn[i];
  if (t < ENC) lb[t] = bn[t];
  __syncthreads();
  int wid = t >> 6, lane = t & 63;
  int nwaves = (blockDim.x >> 6) * gridDim.x;
  int w = blockIdx.x * (blockDim.x >> 6) + wid;
  for (int n = w; n < N_NODES; n += nwaves) {
    const float4* xr4 = (const float4*)(x + n * 8);
    float4 a = xr4[0], b = xr4[1];
    float acc = lb[lane];
    acc += a.x * lw[0 * ENC + lane] + a.y * lw[1 * ENC + lane] +
           a.z * lw[2 * ENC + lane] + a.w * lw[3 * ENC + lane];
    acc += b.x * lw[4 * ENC + lane] + b.y * lw[5 * ENC + lane] +
           b.z * lw[6 * ENC + lane] + b.w * lw[7 * ENC + lane];
    h0[n * ENC + lane] = acc;
  }
}

// ---------------- per-round double GEMM, both stacks: blockIdx.y = stack -------
__global__ void __launch_bounds__(256) k_gemm2(const float* __restrict__ hinA,
                                               const float* __restrict__ hinC,
                                               const float* __restrict__ WlA,
                                               const float* __restrict__ WrA,
                                               const float* __restrict__ bcA,
                                               float* __restrict__ xlA_,
                                               float* __restrict__ xrA_,
                                               const float* __restrict__ WlC,
                                               const float* __restrict__ WrC,
                                               const float* __restrict__ bcC,
                                               float* __restrict__ xlC_,
                                               float* __restrict__ xrC_) {
  const int stk = blockIdx.y;
  const float* hin = stk ? hinC : hinA;
  const float* Wl = stk ? WlC : WlA;
  const float* Wr = stk ? WrC : WrA;
  const float* bc = stk ? bcC : bcA;
  float* xl = stk ? xlC_ : xlA_;
  float* xr = stk ? xrC_ : xrA_;
  __shared__ float lw[2 * ENC * ENC];  // [mat][k][c]
  __shared__ float lh[64 * ENC];       // [local node][k]
  int t = threadIdx.x;
  {  // stage weights: 2048 float4, fully coalesced
    const float4* wl4 = (const float4*)Wl;
    const float4* wr4 = (const float4*)Wr;
    float4* lw4 = (float4*)lw;
#pragma unroll
    for (int i = 0; i < 4; ++i) lw4[t + 256 * i] = wl4[t + 256 * i];
#pragma unroll
    for (int i = 0; i < 4; ++i) lw4[1024 + t + 256 * i] = wr4[t + 256 * i];
  }
  int base = blockIdx.x * 64;  // first node of tile
  {  // stage h tile: 1024 float4, fully coalesced; clamp OOB to a valid index
    const float4* h4 = (const float4*)hin;
    float4* lh4 = (float4*)lh;
    int maxi = N_NODES * 16 - 1;
#pragma unroll
    for (int i = 0; i < 4; ++i) {
      int idx = t + 256 * i;
      int gi = base * 16 + idx;
      if (gi > maxi) gi = maxi;
      lh4[idx] = h4[gi];
    }
  }
  __syncthreads();
  int wid = t >> 6, lane = t & 63;
  int msel = lane >> 5, cc = lane & 31;
  const float2* lw2 = (const float2*)lw;  // (m,k,cc) at m*2048 + k*32 + cc
  float* outp = msel ? xr : xl;
  float2 bcv = make_float2(0.f, 0.f);
  if (msel) bcv = ((const float2*)bc)[cc];  // fold edge-encoder bias into xr
#pragma unroll
  for (int chunk = 0; chunk < 4; ++chunk) {
    int n0 = wid * 16 + chunk * 4;  // local node of this 4-node chunk
    float a00 = 0.f, a01 = 0.f, a10 = 0.f, a11 = 0.f;
    float a20 = 0.f, a21 = 0.f, a30 = 0.f, a31 = 0.f;
    const float4* r0 = (const float4*)(lh + (n0 + 0) * ENC);
    const float4* r1 = (const float4*)(lh + (n0 + 1) * ENC);
    const float4* r2 = (const float4*)(lh + (n0 + 2) * ENC);
    const float4* r3 = (const float4*)(lh + (n0 + 3) * ENC);
#pragma unroll
    for (int k4 = 0; k4 < 16; ++k4) {
      float4 h0 = r0[k4], h1 = r1[k4], h2 = r2[k4], h3 = r3[k4];
      float2 w0 = lw2[msel * 2048 + (k4 * 4 + 0) * 32 + cc];
      float2 w1 = lw2[msel * 2048 + (k4 * 4 + 1) * 32 + cc];
      float2 w2 = lw2[msel * 2048 + (k4 * 4 + 2) * 32 + cc];
      float2 w3 = lw2[msel * 2048 + (k4 * 4 + 3) * 32 + cc];
      a00 += h0.x * w0.x + h0.y * w1.x + h0.z * w2.x + h0.w * w3.x;
      a01 += h0.x * w0.y + h0.y * w1.y + h0.z * w2.y + h0.w * w3.y;
      a10 += h1.x * w0.x + h1.y * w1.x + h1.z * w2.x + h1.w * w3.x;
      a11 += h1.x * w0.y + h1.y * w1.y + h1.z * w2.y + h1.w * w3.y;
      a20 += h2.x * w0.x + h2.y * w1.x + h2.z * w2.x + h2.w * w3.x;
      a21 += h2.x * w0.y + h2.y * w1.y + h2.z * w2.y + h2.w * w3.y;
      a30 += h3.x * w0.x + h3.y * w1.x + h3.z * w2.x + h3.w * w3.x;
      a31 += h3.x * w0.y + h3.y * w1.y + h3.z * w2.y + h3.w * w3.y;
    }
    int ng = base + n0;
    if (ng + 0 < N_NODES) *(float2*)(outp + (size_t)(ng + 0) * ENC + cc * 2) = make_float2(a00 + bcv.x, a01 + bcv.y);
    if (ng + 1 < N_NODES) *(float2*)(outp + (size_t)(ng + 1) * ENC + cc * 2) = make_float2(a10 + bcv.x, a11 + bcv.y);
    if (ng + 2 < N_NODES) *(float2*)(outp + (size_t)(ng + 2) * ENC + cc * 2) = make_float2(a20 + bcv.x, a21 + bcv.y);
    if (ng + 3 < N_NODES) *(float2*)(outp + (size_t)(ng + 3) * ENC + cc * 2) = make_float2(a30 + bcv.x, a31 + bcv.y);
  }
}

// ---------------- fused score + online softmax + aggregate, both stacks -------
// wave = dst node; 4 groups x 16 lanes, each group processes ONE edge with
// float4 channels (4 ch/lane). 4 independent online-softmax chains merged by
// butterfly at node end. Chunk loads of srcs/ea_perm stay coalesced + shfl
// broadcast (NEVER wave-uniform vector loads - round-1 lesson: ~50x fetch
// amplification). Inactive edge slots use p=-inf => exp()=0, exact no-op.
template <int RELU>
__global__ void __launch_bounds__(256) k_attn(
    const int* __restrict__ row_start, const int* __restrict__ srcs,
    const float* __restrict__ ea_perm,
    const float* __restrict__ xla, const float* __restrict__ xra,
    const float* __restrict__ xlc, const float* __restrict__ xrc,
    const float* __restrict__ wca, const float* __restrict__ wcc,
    const float* __restrict__ atta, const float* __restrict__ attc,
    const float* __restrict__ Ba, const float* __restrict__ Bc,
    float* __restrict__ ha, float* __restrict__ hc) {
  const float NEG_INF = __int_as_float(0xff800000u);
  int t = threadIdx.x;
  int wid = t >> 6, lane = t & 63;
  int g = lane >> 4;    // edge slot within wave
  int l16 = lane & 15;  // channel-quad index
  // per-lane channel-quad constants
  float4 wa0 = ((const float4*)(wca + 0 * ENC))[l16];
  float4 wa1 = ((const float4*)(wca + 1 * ENC))[l16];
  float4 wa2 = ((const float4*)(wca + 2 * ENC))[l16];
  float4 wa3 = ((const float4*)(wca + 3 * ENC))[l16];
  float4 wc0 = ((const float4*)(wcc + 0 * ENC))[l16];
  float4 wc1 = ((const float4*)(wcc + 1 * ENC))[l16];
  float4 wc2 = ((const float4*)(wcc + 2 * ENC))[l16];
  float4 wc3 = ((const float4*)(wcc + 3 * ENC))[l16];
  float4 ata = ((const float4*)atta)[l16];
  float4 atc = ((const float4*)attc)[l16];
  float4 bva = ((const float4*)Ba)[l16];
  float4 bvc = ((const float4*)Bc)[l16];
  int nw = (blockDim.x >> 6) * gridDim.x;
  for (int n = blockIdx.x * (blockDim.x >> 6) + wid; n < N_NODES; n += nw) {
    int rs = row_start[n], re = row_start[n + 1];
    float4 outa, outc;
    if (re > rs) {
      float4 xran = ((const float4*)(xra + (size_t)n * ENC))[l16];
      float4 xrcn = ((const float4*)(xrc + (size_t)n * ENC))[l16];
      float ma = -1e30f, mc = -1e30f, dena = 0.f, denc = 0.f;
      float4 acca = make_float4(0.f, 0.f, 0.f, 0.f);
      float4 accc = make_float4(0.f, 0.f, 0.f, 0.f);
      for (int base = rs; base < re; base += 16) {
        int cnt = re - base;
        if (cnt > 16) cnt = 16;
        // cooperative coalesced chunk loads (lane-distributed)
        float eav = (lane < 4 * cnt) ? ea_perm[(size_t)base * 4 + lane] : 0.f;
        int sval = (lane < cnt) ? srcs[base + lane] : 0;
#pragma unroll
        for (int j = 0; j < 4; ++j) {
          if (j * 4 >= cnt) break;  // wave-uniform
          int jj = j * 4 + g;
          bool act = jj < cnt;
          int sn = __shfl(sval, act ? jj : 0);
          float av0 = __shfl(eav, jj * 4 + 0);
          float av1 = __shfl(eav, jj * 4 + 1);
          float av2 = __shfl(eav, jj * 4 + 2);
          float av3 = __shfl(eav, jj * 4 + 3);
          int idx = sn * 16 + l16;
          float4 la = ((const float4*)xla)[idx];
          float4 lc = ((const float4*)xlc)[idx];
          // scores (4 channels/lane), reduce 4 in-lane + 4 shfl steps
          float px = lrelu(la.x + xran.x + av0 * wa0.x + av1 * wa1.x + av2 * wa2.x + av3 * wa3.x) * ata.x;
          px += lrelu(la.y + xran.y + av0 * wa0.y + av1 * wa1.y + av2 * wa2.y + av3 * wa3.y) * ata.y;
          px += lrelu(la.z + xran.z + av0 * wa0.z + av1 * wa1.z + av2 * wa2.z + av3 * wa3.z) * ata.z;
          px += lrelu(la.w + xran.w + av0 * wa0.w + av1 * wa1.w + av2 * wa2.w + av3 * wa3.w) * ata.w;
          float py = lrelu(lc.x + xrcn.x + av0 * wc0.x + av1 * wc1.x + av2 * wc2.x + av3 * wc3.x) * atc.x;
          py += lrelu(lc.y + xrcn.y + av0 * wc0.y + av1 * wc1.y + av2 * wc2.y + av3 * wc3.y) * atc.y;
          py += lrelu(lc.z + xrcn.z + av0 * wc0.z + av1 * wc1.z + av2 * wc2.z + av3 * wc3.z) * atc.z;
          py += lrelu(lc.w + xrcn.w + av0 * wc0.w + av1 * wc1.w + av2 * wc2.w + av3 * wc3.w) * atc.w;
          px += __shfl_xor(px, 1); py += __shfl_xor(py, 1);
          px += __shfl_xor(px, 2); py += __shfl_xor(py, 2);
          px += __shfl_xor(px, 4); py += __shfl_xor(py, 4);
          px += __shfl_xor(px, 8); py += __shfl_xor(py, 8);
          px = act ? px : NEG_INF;
          py = act ? py : NEG_INF;
          // online softmax update (per-group chain)
          float mna = fmaxf(ma, px);
          float sca = __expf(ma - mna);
          float exa = __expf(px - mna);
          dena = dena * sca + exa;
          acca.x = acca.x * sca + exa * la.x;
          acca.y = acca.y * sca + exa * la.y;
          acca.z = acca.z * sca + exa * la.z;
          acca.w = acca.w * sca + exa * la.w;
          ma = mna;
          float mnc = fmaxf(mc, py);
          float scc = __expf(mc - mnc);
          float exc = __expf(py - mnc);
          denc = denc * scc + exc;
          accc.x = accc.x * scc + exc * lc.x;
          accc.y = accc.y * scc + exc * lc.y;
          accc.z = accc.z * scc + exc * lc.z;
          accc.w = accc.w * scc + exc * lc.w;
          mc = mnc;
        }
      }
      // merge the 4 group-states (butterfly over lane distance 16, 32)
#pragma unroll
      for (int d = 16; d <= 32; d <<= 1) {
        float m2 = __shfl_xor(ma, d);
        float dn2 = __shfl_xor(dena, d);
        float a2x = __shfl_xor(acca.x, d), a2y = __shfl_xor(acca.y, d);
        float a2z = __shfl_xor(acca.z, d), a2w = __shfl_xor(acca.w, d);
        float mn = fmaxf(ma, m2);
        float s1 = __expf(ma - mn), s2 = __expf(m2 - mn);
        dena = dena * s1 + dn2 * s2;
        acca.x = acca.x * s1 + a2x * s2;
        acca.y = acca.y * s1 + a2y * s2;
        acca.z = acca.z * s1 + a2z * s2;
        acca.w = acca.w * s1 + a2w * s2;
        ma = mn;
        m2 = __shfl_xor(mc, d);
        dn2 = __shfl_xor(denc, d);
        a2x = __shfl_xor(accc.x, d); a2y = __shfl_xor(accc.y, d);
        a2z = __shfl_xor(accc.z, d); a2w = __shfl_xor(accc.w, d);
        mn = fmaxf(mc, m2);
        s1 = __expf(mc - mn); s2 = __expf(m2 - mn);
        denc = denc * s1 + dn2 * s2;
        accc.x = accc.x * s1 + a2x * s2;
        accc.y = accc.y * s1 + a2y * s2;
        accc.z = accc.z * s1 + a2z * s2;
        accc.w = accc.w * s1 + a2w * s2;
        mc = mn;
      }
      float ia = 1.f / dena, ic = 1.f / denc;
      outa = make_float4(acca.x * ia + bva.x, acca.y * ia + bva.y,
                         acca.z * ia + bva.z, acca.w * ia + bva.w);
      outc = make_float4(accc.x * ic + bvc.x, accc.y * ic + bvc.y,
                         accc.z * ic + bvc.z, accc.w * ic + bvc.w);
    } else {
      outa = bva;
      outc = bvc;
    }
    if (RELU) {
      outa.x = fmaxf(outa.x, 0.f); outa.y = fmaxf(outa.y, 0.f);
      outa.z = fmaxf(outa.z, 0.f); outa.w = fmaxf(outa.w, 0.f);
      outc.x = fmaxf(outc.x, 0.f); outc.y = fmaxf(outc.y, 0.f);
      outc.z = fmaxf(outc.z, 0.f); outc.w = fmaxf(outc.w, 0.f);
    }
    if (g == 0) {
      ((float4*)(ha + (size_t)n * ENC))[l16] = outa;
      ((float4*)(hc + (size_t)n * ENC))[l16] = outc;
    }
  }
}

// ---------------- fused decoders ----------------
__global__ void k_dec(const float* __restrict__ ha, const float* __restrict__ hc,
                      const float* __restrict__ Wa, const float* __restrict__ ba,
                      const float* __restrict__ Wv, const float* __restrict__ bv,
                      float* __restrict__ out) {
  int t = threadIdx.x;
  int wid = t >> 6, lane = t & 63;
  int nw = (blockDim.x >> 6) * gridDim.x;
  int w = blockIdx.x * (blockDim.x >> 6) + wid;
  for (int n = w; n < N_NODES; n += nw) {
    float hva = ha[(size_t)n * ENC + lane];
    float hvc = hc[(size_t)n * ENC + lane];
#pragma unroll
    for (int j = 0; j < 5; ++j) {
      float p = hva * Wa[lane * 5 + j];
      p += __shfl_xor(p, 1);
      p += __shfl_xor(p, 2);
      p += __shfl_xor(p, 4);
      p += __shfl_xor(p, 8);
      p += __shfl_xor(p, 16);
      p += __shfl_xor(p, 32);
      if (lane == 0) out[n * 6 + j] = tanhf(p + ba[j]);
    }
    float p = hvc * Wv[lane];
    p += __shfl_xor(p, 1);
    p += __shfl_xor(p, 2);
    p += __shfl_xor(p, 4);
    p += __shfl_xor(p, 8);
    p += __shfl_xor(p, 16);
    p += __shfl_xor(p, 32);
    if (lane == 0) out[n * 6 + 5] = p + bv[0];
  }
}

extern "C" void kernel_launch(void* const* d_in, const int* in_sizes, int n_in,
                              void* d_out, int out_size, void* d_ws, size_t ws_size,
                              hipStream_t stream) {
  const float* x    = (const float*)d_in[0];
  const float* ea   = (const float*)d_in[1];
  const float* Wn   = (const float*)d_in[2];
  const float* bn   = (const float*)d_in[3];
  const float* Wedg = (const float*)d_in[4];
  const float* bedg = (const float*)d_in[5];
  const float* aWl  = (const float*)d_in[6];
  const float* aWr  = (const float*)d_in[7];
  const float* aWe  = (const float*)d_in[8];
  const float* aAtt = (const float*)d_in[9];
  const float* aB   = (const float*)d_in[10];
  const float* cWl  = (const float*)d_in[11];
  const float* cWr  = (const float*)d_in[12];
  const float* cWe  = (const float*)d_in[13];
  const float* cAtt = (const float*)d_in[14];
  const float* cB   = (const float*)d_in[15];
  const float* Wa   = (const float*)d_in[16];
  const float* ba   = (const float*)d_in[17];
  const float* Wv   = (const float*)d_in[18];
  const float* bv   = (const float*)d_in[19];
  const int* src    = (const int*)d_in[20];
  const int* dst    = (const int*)d_in[21];
  float* out = (float*)d_out;

  char* w = (char*)d_ws;
  size_t off = 0;
  auto alloc = [&](size_t bytes) -> char* {
    char* p = w + off;
    off = (off + bytes + 255) & ~(size_t)255;
    return p;
  };
  float* h0  = (float*)alloc((size_t)N_NODES * ENC * 4);
  float* hA  = (float*)alloc((size_t)N_NODES * ENC * 4);
  float* hC  = (float*)alloc((size_t)N_NODES * ENC * 4);
  float* xlA = (float*)alloc((size_t)N_NODES * ENC * 4);
  float* xrA = (float*)alloc((size_t)N_NODES * ENC * 4);
  float* xlC = (float*)alloc((size_t)N_NODES * ENC * 4);
  float* xrC = (float*)alloc((size_t)N_NODES * ENC * 4);
  int* srcs      = (int*)alloc((size_t)N_EDGES * 4);
  float* ea_perm = (float*)alloc((size_t)N_EDGES * 16);
  int* row_start = (int*)alloc((size_t)(N_NODES + 1) * 4);
  int* cursor    = (int*)alloc((size_t)N_NODES * 4);
  int* part      = (int*)alloc(256 * 4);
  float* wcomb   = (float*)alloc(6 * 4 * ENC * 4);
  float* bcomb   = (float*)alloc(6 * ENC * 4);

  // ---- CSR build ----
  hipMemsetAsync(cursor, 0, (size_t)N_NODES * 4, stream);
  k_hist<<<2048, 256, 0, stream>>>(dst, cursor);
  k_red<<<SCAN_BLOCKS, 256, 0, stream>>>(cursor, part);
  k_scanp<<<1, 256, 0, stream>>>(part);
  k_csr<<<SCAN_BLOCKS, 256, 0, stream>>>(cursor, part, row_start);
  k_scatter<<<2048, 256, 0, stream>>>(src, dst, ea, cursor, srcs, ea_perm);

  // ---- folded edge weights + encoder ----
  k_wcomb<<<1, 256, 0, stream>>>(Wedg, bedg, aWe, cWe, wcomb, bcomb);
  k_encode<<<512, 256, 0, stream>>>(x, Wn, bn, h0);

  const int GEMM_TILES = (N_NODES + 63) / 64;  // 782

  for (int r = 0; r < ROUNDS; ++r) {
    const float* hinA = (r == 0) ? h0 : hA;
    const float* hinC = (r == 0) ? h0 : hC;
    k_gemm2<<<dim3(GEMM_TILES, 2), 256, 0, stream>>>(
        hinA, hinC, aWl + r * ENC * ENC, aWr + r * ENC * ENC, bcomb + r * ENC, xlA, xrA,
        cWl + r * ENC * ENC, cWr + r * ENC * ENC, bcomb + (3 + r) * ENC, xlC, xrC);
    if (r < ROUNDS - 1)
      k_attn<1><<<2048, 256, 0, stream>>>(row_start, srcs, ea_perm, xlA, xrA, xlC, xrC,
                                          wcomb + r * 4 * ENC, wcomb + (3 + r) * 4 * ENC,
                                          aAtt + r * ENC, cAtt + r * ENC,
                                          aB + r * ENC, cB + r * ENC, hA, hC);
    else
      k_attn<0><<<2048, 256, 0, stream>>>(row_start, srcs, ea_perm, xlA, xrA, xlC, xrC,
                                          wcomb + r * 4 * ENC, wcomb + (3 + r) * 4 * ENC,
                                          aAtt + r * ENC, cAtt + r * ENC,
                                          aB + r * ENC, cB + r * ENC, hA, hC);
  }
  k_dec<<<1024, 256, 0, stream>>>(hA, hC, Wa, ba, Wv, bv, out);
}